// Round 14
// baseline (6125.883 us; speedup 1.0000x reference)
//
#include <hip/hip_runtime.h>
#include <hip/hip_bf16.h>

#define NFEAT 512
#define NHID  256
#define NOUT  64
#define NUM_LAYERS 8
#define CH    4      // source-chunk buckets per row (reuse-distance compression)

// ---------------------------------------------------------------------------
// Graph preprocessing. CSR bucketed by (row, col_chunk): bin = row*CH + chunk.
// Each row's edges stay contiguous but grouped by source chunk -> SpMM cohort
// sweeps 25MB source windows (reuse-distance compression; r10 showed capacity
// split alone didn't fix the ~50% L3 miss).
// ---------------------------------------------------------------------------

__global__ void hist_kernel(const int* __restrict__ ei, int E, int M,
                            int* __restrict__ cnt) {
    int e = blockIdx.x * blockDim.x + threadIdx.x;
    if (e >= E) return;
    int r = ei[e];
    int c = ei[E + e];
    int chunk = (c * CH) / M;            // consistent with scatter_kernel
    atomicAdd(&cnt[r * CH + chunk], 1);
}

__global__ void dinv_kernel(const int* __restrict__ rowptr2, float* __restrict__ dinv,
                            int n) {
    int i = blockIdx.x * blockDim.x + threadIdx.x;
    if (i < n) {
        int deg = rowptr2[i * CH + CH] - rowptr2[i * CH];
        dinv[i] = rsqrtf((float)deg + 1.0f);   // +1 = self loop
    }
}

// 4096 elements per 256-thread block, 16 per thread
__global__ __launch_bounds__(256)
void scan_blocks(const int* __restrict__ cnt, int* __restrict__ out,
                 int* __restrict__ partials, int n) {
    __shared__ int sdata[256];
    int tid  = threadIdx.x;
    int base = blockIdx.x * 4096 + tid * 16;
    int v[16];
    int s = 0;
    #pragma unroll
    for (int j = 0; j < 16; ++j) {
        int x = (base + j < n) ? cnt[base + j] : 0;
        s += x;
        v[j] = s;
    }
    sdata[tid] = s;
    __syncthreads();
    #pragma unroll
    for (int off = 1; off < 256; off <<= 1) {
        int t = (tid >= off) ? sdata[tid - off] : 0;
        __syncthreads();
        sdata[tid] += t;
        __syncthreads();
    }
    int excl = sdata[tid] - s;
    #pragma unroll
    for (int j = 0; j < 16; ++j)
        if (base + j < n) out[base + j] = excl + v[j];
    if (tid == 255) partials[blockIdx.x] = sdata[255];
}

__global__ __launch_bounds__(256)
void scan_partials(int* __restrict__ partials, int nb) {
    __shared__ int sdata[256];
    int tid = threadIdx.x;
    int s = (tid < nb) ? partials[tid] : 0;
    sdata[tid] = s;
    __syncthreads();
    #pragma unroll
    for (int off = 1; off < 256; off <<= 1) {
        int t = (tid >= off) ? sdata[tid - off] : 0;
        __syncthreads();
        sdata[tid] += t;
        __syncthreads();
    }
    if (tid < nb) partials[tid] = sdata[tid] - s;
}

__global__ void scan_add(int* __restrict__ rowptr, const int* __restrict__ partials, int n) {
    int i = blockIdx.x * blockDim.x + threadIdx.x;
    if (i == 0) rowptr[0] = 0;
    if (i < n) rowptr[i + 1] += partials[i >> 12];       // 4096 = 2^12
}

__global__ void scatter_kernel(const int* __restrict__ ei, int E, int M,
                               const int* __restrict__ rowptr2, int* __restrict__ fill,
                               const float* __restrict__ dinv,
                               int* __restrict__ csr_col, float* __restrict__ csr_w) {
    int e = blockIdx.x * blockDim.x + threadIdx.x;
    if (e >= E) return;
    int r = ei[e];
    int c = ei[E + e];
    int chunk = (c * CH) / M;
    int bin = r * CH + chunk;
    int pos = rowptr2[bin] + atomicAdd(&fill[bin], 1);
    csr_col[pos] = c;
    csr_w[pos]   = dinv[r] * dinv[c];
}

// ---------------------------------------------------------------------------
// SpMM: one wave per row, 256 feats = 64 x float4 (r5-validated body; beg/end
// from chunked rowptr). mixed = 0.9*(D^-1/2 (A+I) D^-1/2 h) + 0.1*x0
// ---------------------------------------------------------------------------

__global__ __launch_bounds__(256)
void spmm_kernel(const int* __restrict__ rowptr2, const int* __restrict__ csr_col,
                 const float* __restrict__ csr_w, const float* __restrict__ dinv,
                 const float* __restrict__ h, const float* __restrict__ x0,
                 float* __restrict__ mixed, int n) {
    int row = blockIdx.x * 4 + (threadIdx.x >> 6);
    if (row >= n) return;
    int lane = threadIdx.x & 63;
    const float4* hv = (const float4*)h;
    float dr = dinv[row];

    float4 v = hv[(size_t)row * 64 + lane];              // self loop
    float ws = dr * dr;
    float4 acc;
    acc.x = ws * v.x; acc.y = ws * v.y; acc.z = ws * v.z; acc.w = ws * v.w;

    int beg = rowptr2[row * CH], end = rowptr2[row * CH + CH];
    int j = beg;
    for (; j + 3 < end; j += 4) {
        int c0 = __builtin_amdgcn_readfirstlane(csr_col[j + 0]);
        int c1 = __builtin_amdgcn_readfirstlane(csr_col[j + 1]);
        int c2 = __builtin_amdgcn_readfirstlane(csr_col[j + 2]);
        int c3 = __builtin_amdgcn_readfirstlane(csr_col[j + 3]);
        float w0 = csr_w[j + 0], w1 = csr_w[j + 1];
        float w2 = csr_w[j + 2], w3 = csr_w[j + 3];
        float4 u0 = hv[(size_t)c0 * 64 + lane];
        float4 u1 = hv[(size_t)c1 * 64 + lane];
        float4 u2 = hv[(size_t)c2 * 64 + lane];
        float4 u3 = hv[(size_t)c3 * 64 + lane];
        acc.x += w0 * u0.x; acc.y += w0 * u0.y; acc.z += w0 * u0.z; acc.w += w0 * u0.w;
        acc.x += w1 * u1.x; acc.y += w1 * u1.y; acc.z += w1 * u1.z; acc.w += w1 * u1.w;
        acc.x += w2 * u2.x; acc.y += w2 * u2.y; acc.z += w2 * u2.z; acc.w += w2 * u2.w;
        acc.x += w3 * u3.x; acc.y += w3 * u3.y; acc.z += w3 * u3.z; acc.w += w3 * u3.w;
    }
    for (; j < end; ++j) {
        int   c  = __builtin_amdgcn_readfirstlane(csr_col[j]);
        float wc = csr_w[j];
        float4 u = hv[(size_t)c * 64 + lane];
        acc.x += wc * u.x; acc.y += wc * u.y; acc.z += wc * u.z; acc.w += wc * u.w;
    }
    float4 xv = ((const float4*)x0)[(size_t)row * 64 + lane];
    float4 o;
    o.x = 0.9f * acc.x + 0.1f * xv.x;
    o.y = 0.9f * acc.y + 0.1f * xv.y;
    o.z = 0.9f * acc.z + 0.1f * xv.z;
    o.w = 0.9f * acc.w + 0.1f * xv.w;
    ((float4*)mixed)[(size_t)row * 64 + lane] = o;
}

// ---------------------------------------------------------------------------
// fp32 GEMM, LDS-conflict-reduced (r10: BANK_CONFLICT=3.2e7, VALUBusy 61%):
//  - col microtile split x*4 / 64+x*4  -> b-reads 2-way (free) instead of 4-way
//  - LDS rows padded 128->132 floats   -> B-tile staging store 16-way -> 8-way
// Thread->column remap only: each output element sums identical products in
// identical k-order -> bit-identical results. In-place (out==addend) safe.
// ---------------------------------------------------------------------------

#define LDSP 132

template <bool RELU>
__global__ __launch_bounds__(256)
void gemm_kernel(const float* __restrict__ A, const float* __restrict__ W,
                 const float* __restrict__ bias, const float* __restrict__ addend,
                 float* __restrict__ out, float* __restrict__ out2,
                 int M, int K, int Nn) {
    __shared__ float As[16][LDSP];
    __shared__ float Bs[16][LDSP];
    int tid = threadIdx.x;
    int bm = blockIdx.x * 128;
    int bn = blockIdx.y * 128;

    int arow = tid >> 1;
    int acol = (tid & 1) * 8;
    int brow = tid >> 4;
    int bcol = (tid & 15) * 8;
    int x = tid & 15, y = tid >> 4;

    float acc[8][8] = {};

    for (int k0 = 0; k0 < K; k0 += 16) {
        {
            int gr = bm + arow;
            float4 v0 = {0,0,0,0}, v1 = {0,0,0,0};
            if (gr < M) {
                const float* p = A + (size_t)gr * K + k0 + acol;
                v0 = *(const float4*)p;
                v1 = *(const float4*)(p + 4);
            }
            As[acol + 0][arow] = v0.x; As[acol + 1][arow] = v0.y;
            As[acol + 2][arow] = v0.z; As[acol + 3][arow] = v0.w;
            As[acol + 4][arow] = v1.x; As[acol + 5][arow] = v1.y;
            As[acol + 6][arow] = v1.z; As[acol + 7][arow] = v1.w;
        }
        {
            float4 v0 = {0,0,0,0}, v1 = {0,0,0,0};
            if (bn + bcol < Nn) {                      // Nn % 8 == 0
                const float* p = W + (size_t)(k0 + brow) * Nn + bn + bcol;
                v0 = *(const float4*)p;
                v1 = *(const float4*)(p + 4);
            }
            *(float4*)&Bs[brow][bcol]     = v0;
            *(float4*)&Bs[brow][bcol + 4] = v1;
        }
        __syncthreads();
        #pragma unroll
        for (int k = 0; k < 16; ++k) {
            float a[8], b[8];
            *(float4*)&a[0] = *(const float4*)&As[k][y * 8];
            *(float4*)&a[4] = *(const float4*)&As[k][y * 8 + 4];
            *(float4*)&b[0] = *(const float4*)&Bs[k][x * 4];        // cols x*4..+3
            *(float4*)&b[4] = *(const float4*)&Bs[k][64 + x * 4];   // cols 64+x*4..+3
            #pragma unroll
            for (int i = 0; i < 8; ++i)
                #pragma unroll
                for (int j = 0; j < 8; ++j)
                    acc[i][j] = fmaf(a[i], b[j], acc[i][j]);
        }
        __syncthreads();
    }

    #pragma unroll
    for (int i = 0; i < 8; ++i) {
        int gr = bm + y * 8 + i;
        if (gr >= M) continue;
        size_t ro = (size_t)gr * Nn;
        #pragma unroll
        for (int jj = 0; jj < 8; jj += 4) {
            int gc = bn + (jj ? 64 : 0) + x * 4;       // col group per remap
            if (gc >= Nn) continue;                    // Nn % 8 == 0
            float4 v;
            v.x = acc[i][jj + 0]; v.y = acc[i][jj + 1];
            v.z = acc[i][jj + 2]; v.w = acc[i][jj + 3];
            if (bias) {
                float4 bv = *(const float4*)(bias + gc);
                v.x += bv.x; v.y += bv.y; v.z += bv.z; v.w += bv.w;
            }
            if (addend) {
                float4 ad = *(const float4*)(addend + ro + gc);
                v.x += ad.x; v.y += ad.y; v.z += ad.z; v.w += ad.w;
            }
            if (RELU) {
                v.x = fmaxf(v.x, 0.f); v.y = fmaxf(v.y, 0.f);
                v.z = fmaxf(v.z, 0.f); v.w = fmaxf(v.w, 0.f);
            }
            *(float4*)(out + ro + gc) = v;
            if (out2) *(float4*)(out2 + ro + gc) = v;
        }
    }
}

// ---------------------------------------------------------------------------

extern "C" void kernel_launch(void* const* d_in, const int* in_sizes, int n_in,
                              void* d_out, int out_size, void* d_ws, size_t ws_size,
                              hipStream_t stream) {
    const float* x      = (const float*)d_in[0];
    const int*   ei     = (const int*)d_in[1];
    const float* W1     = (const float*)d_in[2];
    const float* b1     = (const float*)d_in[3];
    const float* W2     = (const float*)d_in[4];
    const float* b2     = (const float*)d_in[5];
    const float* conv_w = (const float*)d_in[6];

    const int M = in_sizes[0] / NFEAT;   // 100000
    const int E = in_sizes[1] / 2;       // 3200000
    const int n2 = M * CH;               // 400000 bins

    char* ws = (char*)d_ws;
    size_t off = 0;
    auto alloc = [&](size_t bytes) -> void* {
        off = (off + 255) & ~(size_t)255;
        void* p = ws + off;
        off += bytes;
        return p;
    };
    int*   rowptr2 = (int*)  alloc((size_t)(n2 + 1) * 4);
    float* dinv    = (float*)alloc((size_t)M * 4);
    int*   csr     = (int*)  alloc((size_t)E * 4);
    float* csr_w   = (float*)alloc((size_t)E * 4);
    float* h       = (float*)alloc((size_t)M * NHID * 4);
    float* x0      = (float*)alloc((size_t)M * NHID * 4);
    float* mixed   = (float*)alloc((size_t)M * NHID * 4);

    // cnt/fill/partials alias into `mixed`: dead before layer-0 spmm writes it.
    int* cnt      = (int*)mixed;
    int* fill     = (int*)mixed + n2;
    int* partials = (int*)mixed + 2 * n2;

    // Workspace guard (~335 MB; r5/r10 passed at ~334 MB).
    if (off > ws_size) return;

    hipMemsetAsync(cnt, 0, (size_t)n2 * 2 * 4, stream);   // cnt + fill

    hist_kernel<<<(E + 255) / 256, 256, 0, stream>>>(ei, E, M, cnt);

    int nblocks = (n2 + 4095) / 4096;    // 98 <= 256
    scan_blocks<<<nblocks, 256, 0, stream>>>(cnt, rowptr2 + 1, partials, n2);
    scan_partials<<<1, 256, 0, stream>>>(partials, nblocks);
    scan_add<<<(n2 + 255) / 256, 256, 0, stream>>>(rowptr2, partials, n2);
    dinv_kernel<<<(M + 255) / 256, 256, 0, stream>>>(rowptr2, dinv, M);
    scatter_kernel<<<(E + 255) / 256, 256, 0, stream>>>(ei, E, M, rowptr2, fill, dinv,
                                                        csr, csr_w);

    dim3 g1((M + 127) / 128, (NHID + 127) / 128);
    gemm_kernel<true><<<g1, 256, 0, stream>>>(x, W1, b1, nullptr, h, x0, M, NFEAT, NHID);

    int sgrid = (M + 3) / 4;
    for (int l = 0; l < NUM_LAYERS; ++l) {
        spmm_kernel<<<sgrid, 256, 0, stream>>>(rowptr2, csr, csr_w, dinv, h, x0,
                                               mixed, M);
        gemm_kernel<true><<<g1, 256, 0, stream>>>(mixed, conv_w + (size_t)l * NHID * NHID,
                                                  nullptr, h, h, nullptr, M, NHID, NHID);
    }

    dim3 g2((M + 127) / 128, 1);
    gemm_kernel<true><<<g2, 256, 0, stream>>>(h, W2, b2, nullptr, (float*)d_out, nullptr,
                                              M, NHID, NOUT);
}